// Round 6
// baseline (1856.882 us; speedup 1.0000x reference)
//
#include <hip/hip_runtime.h>
#include <hip/hip_bf16.h>
#include <math.h>

#define L 2048
#define HDIM 2048
#define HV 32
#define HK 16
#define DK 128
#define DV 128
#define KS 4
#define KEY_DIM 2048
#define VALUE_DIM 4096
#define CONV_DIM 8192
#define QKVZ_N 12288
#define EPS 1e-6f
#define CHUNK 16

typedef __attribute__((ext_vector_type(8))) short short8v;   // 8 bf16 = 4 VGPRs
typedef __attribute__((ext_vector_type(4))) float f32x4;

__device__ __forceinline__ float silu_f(float x) { return x / (1.f + __expf(-x)); }

// RNE fp32 -> bf16 (bit pattern), and back. Inputs are finite (no NaN handling).
__device__ __forceinline__ ushort f2bf(float v) {
  unsigned u = __builtin_bit_cast(unsigned, v);
  unsigned r = (u + 0x7FFFu + ((u >> 16) & 1u)) >> 16;
  return (ushort)r;
}
__device__ __forceinline__ float bf2f(ushort b) {
  unsigned u = ((unsigned)b) << 16;
  return __builtin_bit_cast(float, u);
}

// DPP rotate-add within each 16-lane row: x += rotate(x, CTRL). After levels
// 1,2,4,8 every lane of the 16-lane group holds the full group sum.
template <int CTRL>
__device__ __forceinline__ float dpp_rot_add(float x) {
  float y = __int_as_float(__builtin_amdgcn_update_dpp(
      __float_as_int(x), __float_as_int(x), CTRL, 0xF, 0xF, false));
  return x + y;
}
__device__ __forceinline__ float reduce16(float x) {
  x = dpp_rot_add<0x121>(x);  // row_ror:1
  x = dpp_rot_add<0x122>(x);  // row_ror:2
  x = dpp_rot_add<0x124>(x);  // row_ror:4
  x = dpp_rot_add<0x128>(x);  // row_ror:8
  return x;
}

// ---------------- split fp32 -> bf16 hi/lo, elementwise ----------------
__global__ __launch_bounds__(256) void split_f32_bf16(const float* __restrict__ x,
                                                      ushort* __restrict__ hi,
                                                      ushort* __restrict__ lo,
                                                      int n4) {
  const int i = blockIdx.x * 256 + threadIdx.x;
  if (i >= n4) return;
  float4 v = *(const float4*)&x[(size_t)i * 4];
  ushort4 h, l;
  h.x = f2bf(v.x); l.x = f2bf(v.x - bf2f(h.x));
  h.y = f2bf(v.y); l.y = f2bf(v.y - bf2f(h.y));
  h.z = f2bf(v.z); l.z = f2bf(v.z - bf2f(h.z));
  h.w = f2bf(v.w); l.w = f2bf(v.w - bf2f(h.w));
  *(ushort4*)&hi[(size_t)i * 4] = h;
  *(ushort4*)&lo[(size_t)i * 4] = l;
}

// ---------------- transpose + split: W[R][C] fp32 -> T[C][R] bf16 hi/lo ---------
__global__ __launch_bounds__(256) void transpose_split(const float* __restrict__ W,
                                                       ushort* __restrict__ Thi,
                                                       ushort* __restrict__ Tlo,
                                                       int R, int Ccols) {
  __shared__ float tile[32][33];
  const int tx = threadIdx.x & 7, ty = threadIdx.x >> 3;   // 8 x 32
  const int c0 = blockIdx.x * 32, r0 = blockIdx.y * 32;
  float4 v = *(const float4*)&W[(size_t)(r0 + ty) * Ccols + c0 + tx * 4];
  tile[tx * 4 + 0][ty] = v.x;
  tile[tx * 4 + 1][ty] = v.y;
  tile[tx * 4 + 2][ty] = v.z;
  tile[tx * 4 + 3][ty] = v.w;
  __syncthreads();
  float a0 = tile[ty][tx * 4 + 0];
  float a1 = tile[ty][tx * 4 + 1];
  float a2 = tile[ty][tx * 4 + 2];
  float a3 = tile[ty][tx * 4 + 3];
  ushort4 h, l;
  h.x = f2bf(a0); l.x = f2bf(a0 - bf2f(h.x));
  h.y = f2bf(a1); l.y = f2bf(a1 - bf2f(h.y));
  h.z = f2bf(a2); l.z = f2bf(a2 - bf2f(h.z));
  h.w = f2bf(a3); l.w = f2bf(a3 - bf2f(h.w));
  const size_t o = (size_t)(c0 + ty) * R + r0 + tx * 4;
  *(ushort4*)&Thi[o] = h;
  *(ushort4*)&Tlo[o] = l;
}

// ---------------- split-bf16 MFMA GEMM: C[M][N] = A[M][K] * B[N][K]^T ----------
__global__ __launch_bounds__(256) void mfma_gemm_split(
    const ushort* __restrict__ Ahi, const ushort* __restrict__ Alo,
    const ushort* __restrict__ Bhi, const ushort* __restrict__ Blo,
    float* __restrict__ C, int M, int N, int K) {
  __shared__ ushort lds[16384];          // As_hi|As_lo|Bs_hi|Bs_lo, each [128][32]
  ushort* As_hi = lds;
  ushort* As_lo = lds + 4096;
  ushort* Bs_hi = lds + 8192;
  ushort* Bs_lo = lds + 12288;
  const int tid = threadIdx.x;
  const int w = tid >> 6, l = tid & 63;
  const int wr = w >> 1, wc = w & 1;
  const int fl = l & 15, fh = l >> 4;
  const int m0 = blockIdx.y * 128, n0 = blockIdx.x * 128;

  f32x4 acc[4][4];
#pragma unroll
  for (int m = 0; m < 4; m++)
#pragma unroll
    for (int n = 0; n < 4; n++) acc[m][n] = (f32x4){0.f, 0.f, 0.f, 0.f};

  for (int kt = 0; kt < K; kt += 32) {
    __syncthreads();
#pragma unroll
    for (int i = 0; i < 2; i++) {
      const int cb = i * 256 + w * 64;       // wave-uniform base chunk
      const int c = cb + l;
      const int row = c >> 2;
      const int k8 = (c & 3) * 8;
      const size_t aoff = (size_t)(m0 + row) * K + kt + k8;
      const size_t boff = (size_t)(n0 + row) * K + kt + k8;
      __builtin_amdgcn_global_load_lds((const __attribute__((address_space(1))) void*)(Ahi + aoff),
                                       (__attribute__((address_space(3))) void*)(As_hi + cb * 8), 16, 0, 0);
      __builtin_amdgcn_global_load_lds((const __attribute__((address_space(1))) void*)(Alo + aoff),
                                       (__attribute__((address_space(3))) void*)(As_lo + cb * 8), 16, 0, 0);
      __builtin_amdgcn_global_load_lds((const __attribute__((address_space(1))) void*)(Bhi + boff),
                                       (__attribute__((address_space(3))) void*)(Bs_hi + cb * 8), 16, 0, 0);
      __builtin_amdgcn_global_load_lds((const __attribute__((address_space(1))) void*)(Blo + boff),
                                       (__attribute__((address_space(3))) void*)(Bs_lo + cb * 8), 16, 0, 0);
    }
    __syncthreads();

    short8v ah[4], al[4];
#pragma unroll
    for (int m = 0; m < 4; m++) {
      const int r = wr * 64 + m * 16 + fl;
      ah[m] = *(const short8v*)(As_hi + r * 32 + fh * 8);
      al[m] = *(const short8v*)(As_lo + r * 32 + fh * 8);
    }
#pragma unroll
    for (int n = 0; n < 4; n++) {
      const int r = wc * 64 + n * 16 + fl;
      const short8v bh = *(const short8v*)(Bs_hi + r * 32 + fh * 8);
      const short8v bl = *(const short8v*)(Bs_lo + r * 32 + fh * 8);
#pragma unroll
      for (int m = 0; m < 4; m++) {
        acc[m][n] = __builtin_amdgcn_mfma_f32_16x16x32_bf16(ah[m], bh, acc[m][n], 0, 0, 0);
        acc[m][n] = __builtin_amdgcn_mfma_f32_16x16x32_bf16(ah[m], bl, acc[m][n], 0, 0, 0);
        acc[m][n] = __builtin_amdgcn_mfma_f32_16x16x32_bf16(al[m], bh, acc[m][n], 0, 0, 0);
      }
    }
  }

#pragma unroll
  for (int m = 0; m < 4; m++)
#pragma unroll
    for (int n = 0; n < 4; n++)
#pragma unroll
      for (int j = 0; j < 4; j++) {
        const int row = m0 + wr * 64 + m * 16 + fh * 4 + j;
        const int col = n0 + wc * 64 + n * 16 + fl;
        C[(size_t)row * N + col] = acc[m][n][j];
      }
}

// ---------------- small GEMM for ba = hidden @ W_ba (N=64) ----------------
__global__ __launch_bounds__(256) void ba_gemm(const float* __restrict__ hs,
                                               const float* __restrict__ Wba,
                                               float* __restrict__ ba) {
  __shared__ float hrow[2048];
  __shared__ float part[4][64];
  const int t = blockIdx.x;
  const int tid = threadIdx.x;
  const float* hp = hs + (size_t)t * HDIM;
  *(float4*)&hrow[tid * 8]     = *(const float4*)&hp[tid * 8];
  *(float4*)&hrow[tid * 8 + 4] = *(const float4*)&hp[tid * 8 + 4];
  __syncthreads();
  const int c = tid & 63, p = tid >> 6;
  float acc = 0.f;
  const float* wp = Wba + (size_t)(p * 512) * 64 + c;
  for (int k = 0; k < 512; k++) acc = fmaf(hrow[p * 512 + k], wp[(size_t)k * 64], acc);
  part[p][c] = acc;
  __syncthreads();
  if (tid < 64) {
    float r = part[0][tid] + part[1][tid] + part[2][tid] + part[3][tid];
    ba[(size_t)t * 64 + tid] = r;
  }
}

// ---------------- causal depthwise conv (KS=4) + silu ----------------
__global__ __launch_bounds__(256) void conv_silu(const float* __restrict__ proj,
                                                 const float* __restrict__ cw,
                                                 float* __restrict__ out) {
  const int idx = blockIdx.x * 256 + threadIdx.x;  // L * (8192/4)
  const int t = idx >> 11;
  const int c = (idx & 2047) * 4;
  float4 w0 = *(const float4*)&cw[(c + 0) * 4];
  float4 w1 = *(const float4*)&cw[(c + 1) * 4];
  float4 w2 = *(const float4*)&cw[(c + 2) * 4];
  float4 w3 = *(const float4*)&cw[(c + 3) * 4];
  const float4 zero = make_float4(0.f, 0.f, 0.f, 0.f);
  float4 x0 = (t - 3 >= 0) ? *(const float4*)&proj[(size_t)(t - 3) * QKVZ_N + c] : zero;
  float4 x1 = (t - 2 >= 0) ? *(const float4*)&proj[(size_t)(t - 2) * QKVZ_N + c] : zero;
  float4 x2 = (t - 1 >= 0) ? *(const float4*)&proj[(size_t)(t - 1) * QKVZ_N + c] : zero;
  float4 x3 = *(const float4*)&proj[(size_t)t * QKVZ_N + c];
  float4 r;
  r.x = x0.x * w0.x + x1.x * w0.y + x2.x * w0.z + x3.x * w0.w;
  r.y = x0.y * w1.x + x1.y * w1.y + x2.y * w1.z + x3.y * w1.w;
  r.z = x0.z * w2.x + x1.z * w2.y + x2.z * w2.z + x3.z * w2.w;
  r.w = x0.w * w3.x + x1.w * w3.y + x2.w * w3.z + x3.w * w3.w;
  r.x = silu_f(r.x); r.y = silu_f(r.y); r.z = silu_f(r.z); r.w = silu_f(r.w);
  *(float4*)&out[(size_t)t * CONV_DIM + c] = r;
}

// ---------------- in-place l2norm of q,k rows (+ q scale) ----------------
__global__ __launch_bounds__(256) void l2norm_qk(float* __restrict__ conv) {
  const int row = blockIdx.x * 4 + (threadIdx.x >> 6);  // L*32 rows (16 q + 16 k per t)
  const int lane = threadIdx.x & 63;
  const int t = row >> 5;
  const int rem = row & 31;               // 0..15 q-heads, 16..31 k-heads
  const size_t base = (size_t)t * CONV_DIM + (size_t)rem * 128;
  float2 x = *(float2*)&conv[base + lane * 2];
  float ss = x.x * x.x + x.y * x.y;
  ss += __shfl_xor(ss, 1);
  ss += __shfl_xor(ss, 2);
  ss += __shfl_xor(ss, 4);
  ss += __shfl_xor(ss, 8);
  ss += __shfl_xor(ss, 16);
  ss += __shfl_xor(ss, 32);
  float sc = rsqrtf(ss + EPS);
  if (rem < 16) sc *= 0.08838834764831843f;  // DK^-0.5
  x.x *= sc;
  x.y *= sc;
  *(float2*)&conv[base + lane * 2] = x;
}

// ---------------- per-(t,h) gate params: beta = sigmoid(b), eg = exp(g) -------
__global__ __launch_bounds__(256) void gb_kernel(const float* __restrict__ ba,
                                                 const float* __restrict__ dtb,
                                                 const float* __restrict__ Alog,
                                                 float* __restrict__ eg,
                                                 float* __restrict__ beta) {
  const int idx = blockIdx.x * 256 + threadIdx.x;  // L*32
  const int t = idx >> 5, h = idx & 31;
  const float b = ba[(size_t)t * 64 + h];
  const float a = ba[(size_t)t * 64 + 32 + h];
  beta[idx] = 1.f / (1.f + __expf(-b));
  const float x = a + dtb[h];
  const float sp = (x > 20.f) ? x : log1pf(__expf(x));
  eg[idx] = __expf(-__expf(Alog[h]) * sp);   // exp(g), precomputed for the scan
}

// ---------------- sequential delta-rule scan (LDS chunk-staged, pipelined) -----
// Grid: 32 heads * 16 v-groups of 8 columns = 512 blocks, 128 threads (2 waves).
// 16 lanes per column. Chunks of 16 steps double-buffered in LDS. k/q rows are
// split into two [CHUNK][64] arrays so 16-lane b128 reads are 2-way (free).
// Step t+1's LDS reads are issued in registers before step t's compute chain.
__global__ __launch_bounds__(128) void deltanet_scan(const float* __restrict__ conv,
                                                     const float* __restrict__ eg,
                                                     const float* __restrict__ barr,
                                                     float* __restrict__ core) {
  __shared__ float sQ0[2][CHUNK][64];
  __shared__ float sQ1[2][CHUNK][64];
  __shared__ float sK0[2][CHUNK][64];
  __shared__ float sK1[2][CHUNK][64];
  __shared__ float sV[2][CHUNK][8];
  __shared__ float sG[2][CHUNK];
  __shared__ float sB[2][CHUNK];

  const int blk = blockIdx.x;       // 32 heads * 16 v-groups of 8 columns
  const int h = blk >> 4;
  const int vbase = (blk & 15) * 8;
  const int kh = h >> 1;
  const int tid = threadIdx.x;
  const int l = tid & 15;           // lane within column group (k-slice)
  const int cg = tid >> 4;          // column group 0..7
  const int v = vbase + cg;

  float s[8];
#pragma unroll
  for (int j = 0; j < 8; j++) s[j] = 0.f;

  float4 rr4[9];
  float rg = 0.f, rb = 0.f;

  // stage: 16 steps * (32 q + 32 k + 2 v) float4 items = 1056 items, 128 thr
#define STAGE_LOAD(T0)                                                          \
  {                                                                             \
    _Pragma("unroll")                                                           \
    for (int it = 0; it < 9; it++) {                                            \
      const int idx = tid + it * 128;                                           \
      if (idx < 1056) {                                                         \
        const int st = idx / 66;                                                \
        const int rr = idx - st * 66;                                           \
        const size_t toff = (size_t)((T0) + st) * CONV_DIM;                     \
        const float* srcp;                                                      \
        if (rr < 32)      srcp = conv + toff + (size_t)kh * 128 + rr * 4;       \
        else if (rr < 64) srcp = conv + toff + 2048 + (size_t)kh * 128 + (rr - 32) * 4; \
        else              srcp = conv + toff + 4096 + (size_t)h * 128 + vbase + (rr - 64) * 4; \
        rr4[it] = *(const float4*)srcp;                                         \
      }                                                                         \
    }                                                                           \
    if (tid < CHUNK)          rg = eg[(size_t)((T0) + tid) * 32 + h];           \
    else if (tid < 2 * CHUNK) rb = barr[(size_t)((T0) + tid - CHUNK) * 32 + h]; \
  }

  // q float4 rr covers elements [rr*4, rr*4+4): lane lg=rr>>1, half=rr&1
#define STAGE_WRITE(B)                                                          \
  {                                                                             \
    _Pragma("unroll")                                                           \
    for (int it = 0; it < 9; it++) {                                            \
      const int idx = tid + it * 128;                                           \
      if (idx < 1056) {                                                         \
        const int st = idx / 66;                                                \
        const int rr = idx - st * 66;                                           \
        float* dstp;                                                            \
        if (rr < 32)      dstp = (rr & 1) ? &sQ1[B][st][(rr >> 1) * 4]          \
                                          : &sQ0[B][st][(rr >> 1) * 4];         \
        else if (rr < 64) { const int r2 = rr - 32;                             \
                            dstp = (r2 & 1) ? &sK1[B][st][(r2 >> 1) * 4]        \
                                            : &sK0[B][st][(r2 >> 1) * 4]; }     \
        else              dstp = &sV[B][st][(rr - 64) * 4];                     \
        *(float4*)dstp = rr4[it];                                               \
      }                                                                         \
    }                                                                           \
    if (tid < CHUNK)          sG[B][tid] = rg;                                  \
    else if (tid < 2 * CHUNK) sB[B][tid - CHUNK] = rb;                          \
  }

  // prologue: chunk 0 into buffer 0
  STAGE_LOAD(0);
  STAGE_WRITE(0);
  __syncthreads();

  int p = 0;
  for (int c = 0; c < L / CHUNK; c++) {
    const int t0n = (c + 1 < L / CHUNK) ? (c + 1) * CHUNK : c * CHUNK;  // clamped
    STAGE_LOAD(t0n);   // issue next chunk's globals; latency hides under compute

    // register pipeline: step st+1's LDS reads issue before step st's chain
    float4 k0n = *(const float4*)&sK0[p][0][l * 4];
    float4 k1n = *(const float4*)&sK1[p][0][l * 4];
    float4 q0n = *(const float4*)&sQ0[p][0][l * 4];
    float4 q1n = *(const float4*)&sQ1[p][0][l * 4];
    float vtn = sV[p][0][cg];
    float en  = sG[p][0];
    float btn = sB[p][0];

#pragma unroll 4
    for (int st = 0; st < CHUNK; st++) {
      const float4 k0 = k0n, k1 = k1n, q0 = q0n, q1 = q1n;
      const float vt = vtn, e = en, bt = btn;
      const int sn = (st < CHUNK - 1) ? st + 1 : st;
      k0n = *(const float4*)&sK0[p][sn][l * 4];
      k1n = *(const float4*)&sK1[p][sn][l * 4];
      q0n = *(const float4*)&sQ0[p][sn][l * 4];
      q1n = *(const float4*)&sQ1[p][sn][l * 4];
      vtn = sV[p][sn][cg];
      en  = sG[p][sn];
      btn = sB[p][sn];

      // dk = <s, k> : tree form + DPP reduce
      float t0 = s[0] * k0.x, t1 = s[1] * k0.y, t2 = s[2] * k0.z, t3 = s[3] * k0.w;
      float t4 = s[4] * k1.x, t5 = s[5] * k1.y, t6 = s[6] * k1.z, t7 = s[7] * k1.w;
      float dk = ((t0 + t1) + (t2 + t3)) + ((t4 + t5) + (t6 + t7));
      dk = reduce16(dk);

      const float delta = fmaf(-e, dk, vt) * bt;

      s[0] = fmaf(s[0], e, k0.x * delta);
      s[1] = fmaf(s[1], e, k0.y * delta);
      s[2] = fmaf(s[2], e, k0.z * delta);
      s[3] = fmaf(s[3], e, k0.w * delta);
      s[4] = fmaf(s[4], e, k1.x * delta);
      s[5] = fmaf(s[5], e, k1.y * delta);
      s[6] = fmaf(s[6], e, k1.z * delta);
      s[7] = fmaf(s[7], e, k1.w * delta);

      // dq = <s_new, q> : off the critical chain
      float dq = s[0] * q0.x;
      dq = fmaf(s[1], q0.y, dq);
      dq = fmaf(s[2], q0.z, dq);
      dq = fmaf(s[3], q0.w, dq);
      dq = fmaf(s[4], q1.x, dq);
      dq = fmaf(s[5], q1.y, dq);
      dq = fmaf(s[6], q1.z, dq);
      dq = fmaf(s[7], q1.w, dq);
      dq = reduce16(dq);

      if (l == 0) core[(size_t)((c * CHUNK + st) * 32 + h) * 128 + v] = dq;
    }

    STAGE_WRITE(p ^ 1);   // waits vmcnt, writes next chunk
    __syncthreads();
    p ^= 1;
  }
#undef STAGE_LOAD
#undef STAGE_WRITE
}

// ---------------- RMSNorm * norm_w * silu(z) -> split bf16 hi/lo ----------------
__global__ __launch_bounds__(256) void post_kernel(const float* __restrict__ core,
                                                   const float* __restrict__ proj,
                                                   const float* __restrict__ normw,
                                                   ushort* __restrict__ ghi,
                                                   ushort* __restrict__ glo) {
  const int row = blockIdx.x * 4 + (threadIdx.x >> 6);  // L*32
  const int lane = threadIdx.x & 63;
  const int t = row >> 5, h = row & 31;
  const float* cp = core + (size_t)row * 128;
  float2 c = *(float2*)&cp[lane * 2];
  float ss = c.x * c.x + c.y * c.y;
  ss += __shfl_xor(ss, 1);
  ss += __shfl_xor(ss, 2);
  ss += __shfl_xor(ss, 4);
  ss += __shfl_xor(ss, 8);
  ss += __shfl_xor(ss, 16);
  ss += __shfl_xor(ss, 32);
  const float sc = rsqrtf(ss * (1.f / 128.f) + EPS);
  float2 nw = *(float2*)&normw[lane * 2];
  const float* zp = proj + (size_t)t * QKVZ_N + CONV_DIM + (size_t)h * 128;
  float2 z = *(float2*)&zp[lane * 2];
  const float o0 = c.x * sc * nw.x * silu_f(z.x);
  const float o1 = c.y * sc * nw.y * silu_f(z.y);
  ushort2 hh, ll;
  hh.x = f2bf(o0); ll.x = f2bf(o0 - bf2f(hh.x));
  hh.y = f2bf(o1); ll.y = f2bf(o1 - bf2f(hh.y));
  *(ushort2*)&ghi[(size_t)row * 128 + lane * 2] = hh;
  *(ushort2*)&glo[(size_t)row * 128 + lane * 2] = ll;
}

extern "C" void kernel_launch(void* const* d_in, const int* in_sizes, int n_in,
                              void* d_out, int out_size, void* d_ws, size_t ws_size,
                              hipStream_t stream) {
  const float* hs    = (const float*)d_in[0];
  const float* Wqkvz = (const float*)d_in[1];
  const float* Wba   = (const float*)d_in[2];
  const float* convw = (const float*)d_in[3];
  const float* dtb   = (const float*)d_in[4];
  const float* Alog  = (const float*)d_in[5];
  const float* normw = (const float*)d_in[6];
  const float* Wout  = (const float*)d_in[7];
  float* out = (float*)d_out;

  // workspace layout (floats), heavily aliased; total ~236 MB
  float* ws_f = (float*)d_ws;
  float* proj = ws_f;                         // 25165824 f (L x QKVZ_N fp32)
  float* r1   = ws_f + 25165824;              // 25165824 f
  float* r2   = r1 + 25165824;                // 8388608 f
  float* ba   = r2 + 8388608;                 // 131072 f
  float* g    = ba + 131072;                  // 65536 f (exp(g))
  float* beta = g + 65536;                    // 65536 f
  // r1: Wt_hi|Wt_lo during GEMM1; conv|core afterwards (Wt dead)
  ushort* Wt_hi = (ushort*)r1;                // 25165824 bf16
  ushort* Wt_lo = Wt_hi + 25165824;
  float* conv = r1;                           // 16777216 f
  float* core = r1 + 16777216;                // 8388608 f
  // r2: hs_hi|hs_lo during GEMM1; gated_hi|gated_lo afterwards
  ushort* hs_hi = (ushort*)r2;                // 4194304 bf16
  ushort* hs_lo = hs_hi + 4194304;
  ushort* gated_hi = (ushort*)r2;             // 8388608 bf16
  ushort* gated_lo = gated_hi + 8388608;
  // Wout transpose into proj region (proj dead after post_kernel)
  ushort* Wot_hi = (ushort*)proj;             // 8388608 bf16
  ushort* Wot_lo = Wot_hi + 8388608;

  split_f32_bf16<<<4096, 256, 0, stream>>>(hs, hs_hi, hs_lo, 1048576);
  transpose_split<<<dim3(QKVZ_N / 32, HDIM / 32), 256, 0, stream>>>(Wqkvz, Wt_hi, Wt_lo, HDIM, QKVZ_N);
  mfma_gemm_split<<<dim3(QKVZ_N / 128, L / 128), 256, 0, stream>>>(hs_hi, hs_lo, Wt_hi, Wt_lo,
                                                                   proj, L, QKVZ_N, HDIM);
  ba_gemm<<<L, 256, 0, stream>>>(hs, Wba, ba);
  gb_kernel<<<(L * 32) / 256, 256, 0, stream>>>(ba, dtb, Alog, g, beta);
  conv_silu<<<(L * (CONV_DIM / 4)) / 256, 256, 0, stream>>>(proj, convw, conv);
  l2norm_qk<<<(L * 32) / 4, 256, 0, stream>>>(conv);
  deltanet_scan<<<512, 128, 0, stream>>>(conv, g, beta, core);
  post_kernel<<<(L * 32) / 4, 256, 0, stream>>>(core, proj, normw, gated_hi, gated_lo);
  transpose_split<<<dim3(HDIM / 32, VALUE_DIM / 32), 256, 0, stream>>>(Wout, Wot_hi, Wot_lo,
                                                                      VALUE_DIM, HDIM);
  mfma_gemm_split<<<dim3(HDIM / 128, L / 128), 256, 0, stream>>>(gated_hi, gated_lo, Wot_hi, Wot_lo,
                                                                 out, L, HDIM, VALUE_DIM);
}

// Round 9
// 1232.110 us; speedup vs baseline: 1.5071x; 1.5071x over previous
//
#include <hip/hip_runtime.h>
#include <hip/hip_bf16.h>
#include <math.h>

#define L 2048
#define HDIM 2048
#define HV 32
#define HK 16
#define DK 128
#define DV 128
#define KS 4
#define KEY_DIM 2048
#define VALUE_DIM 4096
#define CONV_DIM 8192
#define QKVZ_N 12288
#define EPS 1e-6f
#define CCH 64              // chunk length
#define NCH (L / CCH)       // 32 chunks

typedef __attribute__((ext_vector_type(8))) short short8v;   // 8 bf16 = 4 VGPRs
typedef __attribute__((ext_vector_type(4))) float f32x4;

__device__ __forceinline__ float silu_f(float x) { return x / (1.f + __expf(-x)); }

// RNE fp32 -> bf16 (bit pattern), and back. Inputs are finite (no NaN handling).
__device__ __forceinline__ ushort f2bf(float v) {
  unsigned u = __builtin_bit_cast(unsigned, v);
  unsigned r = (u + 0x7FFFu + ((u >> 16) & 1u)) >> 16;
  return (ushort)r;
}
__device__ __forceinline__ float bf2f(ushort b) {
  unsigned u = ((unsigned)b) << 16;
  return __builtin_bit_cast(float, u);
}

// ---------------- split fp32 -> bf16 hi/lo, elementwise ----------------
__global__ __launch_bounds__(256) void split_f32_bf16(const float* __restrict__ x,
                                                      ushort* __restrict__ hi,
                                                      ushort* __restrict__ lo,
                                                      int n4) {
  const int i = blockIdx.x * 256 + threadIdx.x;
  if (i >= n4) return;
  float4 v = *(const float4*)&x[(size_t)i * 4];
  ushort4 h, l;
  h.x = f2bf(v.x); l.x = f2bf(v.x - bf2f(h.x));
  h.y = f2bf(v.y); l.y = f2bf(v.y - bf2f(h.y));
  h.z = f2bf(v.z); l.z = f2bf(v.z - bf2f(h.z));
  h.w = f2bf(v.w); l.w = f2bf(v.w - bf2f(h.w));
  *(ushort4*)&hi[(size_t)i * 4] = h;
  *(ushort4*)&lo[(size_t)i * 4] = l;
}

// ---------------- transpose + split: W[R][C] fp32 -> T[C][R] bf16 hi/lo ---------
__global__ __launch_bounds__(256) void transpose_split(const float* __restrict__ W,
                                                       ushort* __restrict__ Thi,
                                                       ushort* __restrict__ Tlo,
                                                       int R, int Ccols) {
  __shared__ float tile[32][33];
  const int tx = threadIdx.x & 7, ty = threadIdx.x >> 3;   // 8 x 32
  const int c0 = blockIdx.x * 32, r0 = blockIdx.y * 32;
  float4 v = *(const float4*)&W[(size_t)(r0 + ty) * Ccols + c0 + tx * 4];
  tile[tx * 4 + 0][ty] = v.x;
  tile[tx * 4 + 1][ty] = v.y;
  tile[tx * 4 + 2][ty] = v.z;
  tile[tx * 4 + 3][ty] = v.w;
  __syncthreads();
  float a0 = tile[ty][tx * 4 + 0];
  float a1 = tile[ty][tx * 4 + 1];
  float a2 = tile[ty][tx * 4 + 2];
  float a3 = tile[ty][tx * 4 + 3];
  ushort4 h, l;
  h.x = f2bf(a0); l.x = f2bf(a0 - bf2f(h.x));
  h.y = f2bf(a1); l.y = f2bf(a1 - bf2f(h.y));
  h.z = f2bf(a2); l.z = f2bf(a2 - bf2f(h.z));
  h.w = f2bf(a3); l.w = f2bf(a3 - bf2f(h.w));
  const size_t o = (size_t)(c0 + ty) * R + r0 + tx * 4;
  *(ushort4*)&Thi[o] = h;
  *(ushort4*)&Tlo[o] = l;
}

// ---------------- split-bf16 MFMA GEMM: C[M][N] = A[M][K] * B[N][K]^T ----------
__global__ __launch_bounds__(256) void mfma_gemm_split(
    const ushort* __restrict__ Ahi, const ushort* __restrict__ Alo,
    const ushort* __restrict__ Bhi, const ushort* __restrict__ Blo,
    float* __restrict__ C, int M, int N, int K) {
  __shared__ ushort lds[16384];          // As_hi|As_lo|Bs_hi|Bs_lo, each [128][32]
  ushort* As_hi = lds;
  ushort* As_lo = lds + 4096;
  ushort* Bs_hi = lds + 8192;
  ushort* Bs_lo = lds + 12288;
  const int tid = threadIdx.x;
  const int w = tid >> 6, l = tid & 63;
  const int wr = w >> 1, wc = w & 1;
  const int fl = l & 15, fh = l >> 4;
  const int m0 = blockIdx.y * 128, n0 = blockIdx.x * 128;

  f32x4 acc[4][4];
#pragma unroll
  for (int m = 0; m < 4; m++)
#pragma unroll
    for (int n = 0; n < 4; n++) acc[m][n] = (f32x4){0.f, 0.f, 0.f, 0.f};

  for (int kt = 0; kt < K; kt += 32) {
    __syncthreads();
#pragma unroll
    for (int i = 0; i < 2; i++) {
      const int cb = i * 256 + w * 64;       // wave-uniform base chunk
      const int c = cb + l;
      const int row = c >> 2;
      const int k8 = (c & 3) * 8;
      const size_t aoff = (size_t)(m0 + row) * K + kt + k8;
      const size_t boff = (size_t)(n0 + row) * K + kt + k8;
      __builtin_amdgcn_global_load_lds((const __attribute__((address_space(1))) void*)(Ahi + aoff),
                                       (__attribute__((address_space(3))) void*)(As_hi + cb * 8), 16, 0, 0);
      __builtin_amdgcn_global_load_lds((const __attribute__((address_space(1))) void*)(Alo + aoff),
                                       (__attribute__((address_space(3))) void*)(As_lo + cb * 8), 16, 0, 0);
      __builtin_amdgcn_global_load_lds((const __attribute__((address_space(1))) void*)(Bhi + boff),
                                       (__attribute__((address_space(3))) void*)(Bs_hi + cb * 8), 16, 0, 0);
      __builtin_amdgcn_global_load_lds((const __attribute__((address_space(1))) void*)(Blo + boff),
                                       (__attribute__((address_space(3))) void*)(Bs_lo + cb * 8), 16, 0, 0);
    }
    __syncthreads();

    short8v ah[4], al[4];
#pragma unroll
    for (int m = 0; m < 4; m++) {
      const int r = wr * 64 + m * 16 + fl;
      ah[m] = *(const short8v*)(As_hi + r * 32 + fh * 8);
      al[m] = *(const short8v*)(As_lo + r * 32 + fh * 8);
    }
#pragma unroll
    for (int n = 0; n < 4; n++) {
      const int r = wc * 64 + n * 16 + fl;
      const short8v bh = *(const short8v*)(Bs_hi + r * 32 + fh * 8);
      const short8v bl = *(const short8v*)(Bs_lo + r * 32 + fh * 8);
#pragma unroll
      for (int m = 0; m < 4; m++) {
        acc[m][n] = __builtin_amdgcn_mfma_f32_16x16x32_bf16(ah[m], bh, acc[m][n], 0, 0, 0);
        acc[m][n] = __builtin_amdgcn_mfma_f32_16x16x32_bf16(ah[m], bl, acc[m][n], 0, 0, 0);
        acc[m][n] = __builtin_amdgcn_mfma_f32_16x16x32_bf16(al[m], bh, acc[m][n], 0, 0, 0);
      }
    }
  }

#pragma unroll
  for (int m = 0; m < 4; m++)
#pragma unroll
    for (int n = 0; n < 4; n++)
#pragma unroll
      for (int j = 0; j < 4; j++) {
        const int row = m0 + wr * 64 + m * 16 + fh * 4 + j;
        const int col = n0 + wc * 64 + n * 16 + fl;
        C[(size_t)row * N + col] = acc[m][n][j];
      }
}

// ---------------- small GEMM for ba = hidden @ W_ba (N=64) ----------------
__global__ __launch_bounds__(256) void ba_gemm(const float* __restrict__ hs,
                                               const float* __restrict__ Wba,
                                               float* __restrict__ ba) {
  __shared__ float hrow[2048];
  __shared__ float part[4][64];
  const int t = blockIdx.x;
  const int tid = threadIdx.x;
  const float* hp = hs + (size_t)t * HDIM;
  *(float4*)&hrow[tid * 8]     = *(const float4*)&hp[tid * 8];
  *(float4*)&hrow[tid * 8 + 4] = *(const float4*)&hp[tid * 8 + 4];
  __syncthreads();
  const int c = tid & 63, p = tid >> 6;
  float acc = 0.f;
  const float* wp = Wba + (size_t)(p * 512) * 64 + c;
  for (int k = 0; k < 512; k++) acc = fmaf(hrow[p * 512 + k], wp[(size_t)k * 64], acc);
  part[p][c] = acc;
  __syncthreads();
  if (tid < 64) {
    float r = part[0][tid] + part[1][tid] + part[2][tid] + part[3][tid];
    ba[(size_t)t * 64 + tid] = r;
  }
}

// ---------------- causal depthwise conv (KS=4) + silu ----------------
__global__ __launch_bounds__(256) void conv_silu(const float* __restrict__ proj,
                                                 const float* __restrict__ cw,
                                                 float* __restrict__ out) {
  const int idx = blockIdx.x * 256 + threadIdx.x;  // L * (8192/4)
  const int t = idx >> 11;
  const int c = (idx & 2047) * 4;
  float4 w0 = *(const float4*)&cw[(c + 0) * 4];
  float4 w1 = *(const float4*)&cw[(c + 1) * 4];
  float4 w2 = *(const float4*)&cw[(c + 2) * 4];
  float4 w3 = *(const float4*)&cw[(c + 3) * 4];
  const float4 zero = make_float4(0.f, 0.f, 0.f, 0.f);
  float4 x0 = (t - 3 >= 0) ? *(const float4*)&proj[(size_t)(t - 3) * QKVZ_N + c] : zero;
  float4 x1 = (t - 2 >= 0) ? *(const float4*)&proj[(size_t)(t - 2) * QKVZ_N + c] : zero;
  float4 x2 = (t - 1 >= 0) ? *(const float4*)&proj[(size_t)(t - 1) * QKVZ_N + c] : zero;
  float4 x3 = *(const float4*)&proj[(size_t)t * QKVZ_N + c];
  float4 r;
  r.x = x0.x * w0.x + x1.x * w0.y + x2.x * w0.z + x3.x * w0.w;
  r.y = x0.y * w1.x + x1.y * w1.y + x2.y * w1.z + x3.y * w1.w;
  r.z = x0.z * w2.x + x1.z * w2.y + x2.z * w2.z + x3.z * w2.w;
  r.w = x0.w * w3.x + x1.w * w3.y + x2.w * w3.z + x3.w * w3.w;
  r.x = silu_f(r.x); r.y = silu_f(r.y); r.z = silu_f(r.z); r.w = silu_f(r.w);
  *(float4*)&out[(size_t)t * CONV_DIM + c] = r;
}

// ---------------- in-place l2norm of q,k rows (+ q scale) ----------------
__global__ __launch_bounds__(256) void l2norm_qk(float* __restrict__ conv) {
  const int row = blockIdx.x * 4 + (threadIdx.x >> 6);  // L*32 rows (16 q + 16 k per t)
  const int lane = threadIdx.x & 63;
  const int t = row >> 5;
  const int rem = row & 31;               // 0..15 q-heads, 16..31 k-heads
  const size_t base = (size_t)t * CONV_DIM + (size_t)rem * 128;
  float2 x = *(float2*)&conv[base + lane * 2];
  float ss = x.x * x.x + x.y * x.y;
  ss += __shfl_xor(ss, 1);
  ss += __shfl_xor(ss, 2);
  ss += __shfl_xor(ss, 4);
  ss += __shfl_xor(ss, 8);
  ss += __shfl_xor(ss, 16);
  ss += __shfl_xor(ss, 32);
  float sc = rsqrtf(ss + EPS);
  if (rem < 16) sc *= 0.08838834764831843f;  // DK^-0.5
  x.x *= sc;
  x.y *= sc;
  *(float2*)&conv[base + lane * 2] = x;
}

// ---------------- per-(t,h) gate params: beta = sigmoid(b), graw = g (log) ------
__global__ __launch_bounds__(256) void gb_kernel(const float* __restrict__ ba,
                                                 const float* __restrict__ dtb,
                                                 const float* __restrict__ Alog,
                                                 float* __restrict__ graw,
                                                 float* __restrict__ beta) {
  const int idx = blockIdx.x * 256 + threadIdx.x;  // L*32
  const int t = idx >> 5, h = idx & 31;
  const float b = ba[(size_t)t * 64 + h];
  const float a = ba[(size_t)t * 64 + 32 + h];
  beta[idx] = 1.f / (1.f + __expf(-b));
  const float x = a + dtb[h];
  const float sp = (x > 20.f) ? x : log1pf(__expf(x));
  graw[idx] = -__expf(Alog[h]) * sp;   // log-decay g
}

// ---------------- chunked delta-rule, phase A1: per-(chunk,head) T matrix ------
// A[i][j] = beta_i * exp(cg_i - cg_j) * (k_i . k_j)  (j < i, strictly lower)
// T = (I + A)^{-1} by forward substitution. Also writes cumg (inclusive prefix g).
__global__ __launch_bounds__(256) void prep_T(const float* __restrict__ conv,
                                              const float* __restrict__ graw,
                                              const float* __restrict__ beta,
                                              float* __restrict__ cumg,
                                              float* __restrict__ Tg) {
  __shared__ float sK[64][132];
  __shared__ float sA[64][68];
  __shared__ float sT[64][68];
  __shared__ float scg[64];
  __shared__ float sbeta[64];
  const int c = blockIdx.x >> 5, h = blockIdx.x & 31, kh = h >> 1;
  const int tid = threadIdx.x;
  const int t0 = c * CCH;

  if (tid < 64) {
    float x = graw[(size_t)(t0 + tid) * 32 + h];
#pragma unroll
    for (int ofs = 1; ofs < 64; ofs <<= 1) {
      float y = __shfl_up(x, ofs);
      if ((tid & 63) >= ofs) x += y;
    }
    scg[tid] = x;
    cumg[((size_t)c * 32 + h) * 64 + tid] = x;
    sbeta[tid] = beta[(size_t)(t0 + tid) * 32 + h];
  }
  // stage K chunk: 8192 floats / 256 thr = 32 each
  {
    const int i = tid >> 2, a0 = (tid & 3) * 32;
    const float* src = conv + (size_t)(t0 + i) * CONV_DIM + 2048 + (size_t)kh * 128 + a0;
#pragma unroll
    for (int u = 0; u < 8; u++) *(float4*)&sK[i][a0 + u * 4] = *(const float4*)&src[u * 4];
  }
  __syncthreads();
  // A entries: 4096 / 256 = 16 each (row ii, cols jj0..jj0+16)
  {
    const int ii = tid >> 2, jj0 = (tid & 3) * 16;
    const float bi = sbeta[ii];
    const float cgi = scg[ii];
#pragma unroll 4
    for (int e = 0; e < 16; e++) {
      const int jj = jj0 + e;
      float dot = 0.f;
      for (int a = 0; a < 128; a += 4) {
        float4 ki = *(const float4*)&sK[ii][a];
        float4 kj = *(const float4*)&sK[jj][a];
        dot = fmaf(ki.x, kj.x, dot);
        dot = fmaf(ki.y, kj.y, dot);
        dot = fmaf(ki.z, kj.z, dot);
        dot = fmaf(ki.w, kj.w, dot);
      }
      sA[ii][jj] = (jj < ii) ? bi * __expf(cgi - scg[jj]) * dot : 0.f;
    }
  }
  __syncthreads();
  // forward substitution (lane j owns column j; reads only its own prior writes)
  if (tid < 64) {
    const int j = tid;
    sT[0][j] = (j == 0) ? 1.f : 0.f;
    for (int i = 1; i < 64; i++) {
      float acc = 0.f;
      for (int m = 0; m < i; m++) acc = fmaf(sA[i][m], sT[m][j], acc);
      sT[i][j] = ((i == j) ? 1.f : 0.f) - acc;
    }
  }
  __syncthreads();
  // write T
  {
    const int ii = tid >> 2, jj0 = (tid & 3) * 16;
    float* dst = Tg + (((size_t)c * 32 + h) * 64 + ii) * 64 + jj0;
#pragma unroll
    for (int e = 0; e < 16; e += 4)
      *(float4*)&dst[e] = make_float4(sT[ii][jj0 + e], sT[ii][jj0 + e + 1],
                                      sT[ii][jj0 + e + 2], sT[ii][jj0 + e + 3]);
  }
}

// ---------------- phase A2: M[i][j] = exp(cg_i - cg_j) * (q_i . k_j), j<=i ------
__global__ __launch_bounds__(256) void prep_M(const float* __restrict__ conv,
                                              const float* __restrict__ cumg,
                                              float* __restrict__ Mg) {
  __shared__ float sK[64][132];
  __shared__ float sQ[64][132];
  __shared__ float scg[64];
  const int c = blockIdx.x >> 5, h = blockIdx.x & 31, kh = h >> 1;
  const int tid = threadIdx.x;
  const int t0 = c * CCH;
  if (tid < 64) scg[tid] = cumg[((size_t)c * 32 + h) * 64 + tid];
  {
    const int i = tid >> 2, a0 = (tid & 3) * 32;
    const float* srck = conv + (size_t)(t0 + i) * CONV_DIM + 2048 + (size_t)kh * 128 + a0;
    const float* srcq = conv + (size_t)(t0 + i) * CONV_DIM + (size_t)kh * 128 + a0;
#pragma unroll
    for (int u = 0; u < 8; u++) {
      *(float4*)&sK[i][a0 + u * 4] = *(const float4*)&srck[u * 4];
      *(float4*)&sQ[i][a0 + u * 4] = *(const float4*)&srcq[u * 4];
    }
  }
  __syncthreads();
  {
    const int ii = tid >> 2, jj0 = (tid & 3) * 16;
    const float cgi = scg[ii];
    float* dst = Mg + (((size_t)c * 32 + h) * 64 + ii) * 64 + jj0;
#pragma unroll 4
    for (int e = 0; e < 16; e++) {
      const int jj = jj0 + e;
      float dot = 0.f;
      for (int a = 0; a < 128; a += 4) {
        float4 qi = *(const float4*)&sQ[ii][a];
        float4 kj = *(const float4*)&sK[jj][a];
        dot = fmaf(qi.x, kj.x, dot);
        dot = fmaf(qi.y, kj.y, dot);
        dot = fmaf(qi.z, kj.z, dot);
        dot = fmaf(qi.w, kj.w, dot);
      }
      dst[e] = (jj <= ii) ? __expf(cgi - scg[jj]) * dot : 0.f;
    }
  }
}

// ---------------- phase B: sequential chunk loop, parallel over (head, v-tile) --
// Block = (head h, v-tile of 16 cols). S[128][16] persists in LDS across chunks.
// Per chunk: P=K*S0, RHS=B(V-Gamma*P), Delta=T*RHS, O=Gamma*Q*S0+M*Delta, S update.
__global__ __launch_bounds__(512) void chunk_scan(const float* __restrict__ conv,
                                                  const float* __restrict__ cumg,
                                                  const float* __restrict__ beta,
                                                  const float* __restrict__ Tg,
                                                  const float* __restrict__ Mg,
                                                  float* __restrict__ core) {
  __shared__ float sS[128][20];
  __shared__ float sK[64][132];
  __shared__ float sQ[64][132];
  __shared__ float sT[64][68];
  __shared__ float sM[64][68];
  __shared__ float sRHS[64][20];
  __shared__ float sDelta[64][20];
  __shared__ float scg[64];
  __shared__ float sbeta[64];
  __shared__ float sEW[64];

  const int h = blockIdx.x >> 3, bt = blockIdx.x & 7;
  const int b0col = bt * 16;
  const int kh = h >> 1;
  const int tid = threadIdx.x;

  // init S = 0
  {
    const int a = tid & 127, bq = tid >> 7;
#pragma unroll
    for (int u = 0; u < 4; u++) sS[a][bq * 4 + u] = 0.f;
  }
  __syncthreads();

  for (int c = 0; c < NCH; c++) {
    const int t0 = c * CCH;
    // ---- stage K, Q (16 floats each), T, M (8 floats each), cg/beta ----
    {
      const int i = tid >> 3, a0 = (tid & 7) * 16;
      const float* srck = conv + (size_t)(t0 + i) * CONV_DIM + 2048 + (size_t)kh * 128 + a0;
      const float* srcq = conv + (size_t)(t0 + i) * CONV_DIM + (size_t)kh * 128 + a0;
#pragma unroll
      for (int u = 0; u < 4; u++) {
        *(float4*)&sK[i][a0 + u * 4] = *(const float4*)&srck[u * 4];
        *(float4*)&sQ[i][a0 + u * 4] = *(const float4*)&srcq[u * 4];
      }
      const int ii = tid >> 3, jj0 = (tid & 7) * 8;
      const float* tp = Tg + (((size_t)c * 32 + h) * 64 + ii) * 64 + jj0;
      const float* mp = Mg + (((size_t)c * 32 + h) * 64 + ii) * 64 + jj0;
      *(float4*)&sT[ii][jj0]     = *(const float4*)&tp[0];
      *(float4*)&sT[ii][jj0 + 4] = *(const float4*)&tp[4];
      *(float4*)&sM[ii][jj0]     = *(const float4*)&mp[0];
      *(float4*)&sM[ii][jj0 + 4] = *(const float4*)&mp[4];
      if (tid < 64) {
        scg[tid] = cumg[((size_t)c * 32 + h) * 64 + tid];
        sbeta[tid] = beta[(size_t)(t0 + tid) * 32 + h];
      }
    }
    __syncthreads();
    if (tid < 64) sEW[tid] = __expf(scg[63] - scg[tid]);

    const int i = tid >> 3, bp = tid & 7;
    const int t = t0 + i;
    // ---- P = K.S0, O1 = Q.S0 (2 cols each) ----
    float P0 = 0.f, P1 = 0.f, Q0 = 0.f, Q1 = 0.f;
    for (int a = 0; a < 128; a += 4) {
      float4 kv = *(const float4*)&sK[i][a];
      float4 qv = *(const float4*)&sQ[i][a];
      float2 s0 = *(const float2*)&sS[a + 0][bp * 2];
      float2 s1 = *(const float2*)&sS[a + 1][bp * 2];
      float2 s2 = *(const float2*)&sS[a + 2][bp * 2];
      float2 s3 = *(const float2*)&sS[a + 3][bp * 2];
      P0 = fmaf(kv.x, s0.x, P0); P1 = fmaf(kv.x, s0.y, P1);
      Q0 = fmaf(qv.x, s0.x, Q0); Q1 = fmaf(qv.x, s0.y, Q1);
      P0 = fmaf(kv.y, s1.x, P0); P1 = fmaf(kv.y, s1.y, P1);
      Q0 = fmaf(qv.y, s1.x, Q0); Q1 = fmaf(qv.y, s1.y, Q1);
      P0 = fmaf(kv.z, s2.x, P0); P1 = fmaf(kv.z, s2.y, P1);
      Q0 = fmaf(qv.z, s2.x, Q0); Q1 = fmaf(qv.z, s2.y, Q1);
      P0 = fmaf(kv.w, s3.x, P0); P1 = fmaf(kv.w, s3.y, P1);
      Q0 = fmaf(qv.w, s3.x, Q0); Q1 = fmaf(qv.w, s3.y, Q1);
    }
    const float gi = __expf(scg[i]);
    const float bi = sbeta[i];
    float2 vv = *(const float2*)&conv[(size_t)t * CONV_DIM + 4096 + (size_t)h * 128 + b0col + bp * 2];
    sRHS[i][bp * 2]     = bi * (vv.x - gi * P0);
    sRHS[i][bp * 2 + 1] = bi * (vv.y - gi * P1);
    float o0 = gi * Q0, o1 = gi * Q1;
    __syncthreads();
    // ---- Delta = T * RHS ----
    float d0 = 0.f, d1 = 0.f;
    for (int m = 0; m < 64; m++) {
      const float tv = sT[i][m];
      float2 rv = *(const float2*)&sRHS[m][bp * 2];
      d0 = fmaf(tv, rv.x, d0);
      d1 = fmaf(tv, rv.y, d1);
    }
    sDelta[i][bp * 2] = d0;
    sDelta[i][bp * 2 + 1] = d1;
    __syncthreads();
    // ---- O = gamma*Q.S0 + M*Delta ----
    for (int j = 0; j < 64; j++) {
      const float mv = sM[i][j];
      float2 dv = *(const float2*)&sDelta[j][bp * 2];
      o0 = fmaf(mv, dv.x, o0);
      o1 = fmaf(mv, dv.y, o1);
    }
    *(float2*)&core[((size_t)t * 32 + h) * 128 + b0col + bp * 2] = make_float2(o0, o1);
    // ---- S = gend*S + sum_j EW_j k_j Delta_j ----
    {
      const int a = tid & 127, bq = tid >> 7;
      const float gend = __expf(scg[63]);
      float a0 = gend * sS[a][bq * 4 + 0];
      float a1 = gend * sS[a][bq * 4 + 1];
      float a2 = gend * sS[a][bq * 4 + 2];
      float a3 = gend * sS[a][bq * 4 + 3];
      for (int j = 0; j < 64; j++) {
        const float kw = sEW[j] * sK[j][a];
        float4 dv = *(const float4*)&sDelta[j][bq * 4];
        a0 = fmaf(kw, dv.x, a0);
        a1 = fmaf(kw, dv.y, a1);
        a2 = fmaf(kw, dv.z, a2);
        a3 = fmaf(kw, dv.w, a3);
      }
      sS[a][bq * 4 + 0] = a0;
      sS[a][bq * 4 + 1] = a1;
      sS[a][bq * 4 + 2] = a2;
      sS[a][bq * 4 + 3] = a3;
    }
    __syncthreads();
  }
}

// ---------------- RMSNorm * norm_w * silu(z) -> split bf16 hi/lo ----------------
__global__ __launch_bounds__(256) void post_kernel(const float* __restrict__ core,
                                                   const float* __restrict__ proj,
                                                   const float* __restrict__ normw,
                                                   ushort* __restrict__ ghi,
                                                   ushort* __restrict__ glo) {
  const int row = blockIdx.x * 4 + (threadIdx.x >> 6);  // L*32
  const int lane = threadIdx.x & 63;
  const int t = row >> 5, h = row & 31;
  const float* cp = core + (size_t)row * 128;
  float2 c = *(float2*)&cp[lane * 2];
  float ss = c.x * c.x + c.y * c.y;
  ss += __shfl_xor(ss, 1);
  ss += __shfl_xor(ss, 2);
  ss += __shfl_xor(ss, 4);
  ss += __shfl_xor(ss, 8);
  ss += __shfl_xor(ss, 16);
  ss += __shfl_xor(ss, 32);
  const float sc = rsqrtf(ss * (1.f / 128.f) + EPS);
  float2 nw = *(float2*)&normw[lane * 2];
  const float* zp = proj + (size_t)t * QKVZ_N + CONV_DIM + (size_t)h * 128;
  float2 z = *(float2*)&zp[lane * 2];
  const float o0 = c.x * sc * nw.x * silu_f(z.x);
  const float o1 = c.y * sc * nw.y * silu_f(z.y);
  ushort2 hh, ll;
  hh.x = f2bf(o0); ll.x = f2bf(o0 - bf2f(hh.x));
  hh.y = f2bf(o1); ll.y = f2bf(o1 - bf2f(hh.y));
  *(ushort2*)&ghi[(size_t)row * 128 + lane * 2] = hh;
  *(ushort2*)&glo[(size_t)row * 128 + lane * 2] = ll;
}

extern "C" void kernel_launch(void* const* d_in, const int* in_sizes, int n_in,
                              void* d_out, int out_size, void* d_ws, size_t ws_size,
                              hipStream_t stream) {
  const float* hs    = (const float*)d_in[0];
  const float* Wqkvz = (const float*)d_in[1];
  const float* Wba   = (const float*)d_in[2];
  const float* convw = (const float*)d_in[3];
  const float* dtb   = (const float*)d_in[4];
  const float* Alog  = (const float*)d_in[5];
  const float* normw = (const float*)d_in[6];
  const float* Wout  = (const float*)d_in[7];
  float* out = (float*)d_out;

  // workspace layout (floats), heavily aliased; total ~236.2 MB
  float* ws_f = (float*)d_ws;
  float* proj = ws_f;                         // 25165824 f (L x QKVZ_N fp32)
  float* r1   = ws_f + 25165824;              // 25165824 f
  float* r2   = r1 + 25165824;                // 8388608 f
  float* ba   = r2 + 8388608;                 // 131072 f
  float* graw = ba + 131072;                  // 65536 f (log-decay g)
  float* beta = graw + 65536;                 // 65536 f
  float* cumg = beta + 65536;                 // 65536 f (32 chunks x 32 h x 64)
  // r1: Wt_hi|Wt_lo during GEMM1; conv|core afterwards (Wt dead)
  ushort* Wt_hi = (ushort*)r1;                // 25165824 bf16
  ushort* Wt_lo = Wt_hi + 25165824;
  float* conv = r1;                           // 16777216 f
  float* core = r1 + 16777216;                // 8388608 f
  // r2: hs_hi|hs_lo during GEMM1; T|M during scan; gated_hi|lo after post
  ushort* hs_hi = (ushort*)r2;                // 4194304 bf16
  ushort* hs_lo = hs_hi + 4194304;
  float* Tg = r2;                             // 4194304 f (32x32x64x64)
  float* Mg = r2 + 4194304;                   // 4194304 f
  ushort* gated_hi = (ushort*)r2;             // 8388608 bf16
  ushort* gated_lo = gated_hi + 8388608;
  // Wout transpose into proj region (proj dead after post_kernel)
  ushort* Wot_hi = (ushort*)proj;             // 8388608 bf16
  ushort* Wot_lo = Wot_hi + 8388608;

  split_f32_bf16<<<4096, 256, 0, stream>>>(hs, hs_hi, hs_lo, 1048576);
  transpose_split<<<dim3(QKVZ_N / 32, HDIM / 32), 256, 0, stream>>>(Wqkvz, Wt_hi, Wt_lo, HDIM, QKVZ_N);
  mfma_gemm_split<<<dim3(QKVZ_N / 128, L / 128), 256, 0, stream>>>(hs_hi, hs_lo, Wt_hi, Wt_lo,
                                                                   proj, L, QKVZ_N, HDIM);
  ba_gemm<<<L, 256, 0, stream>>>(hs, Wba, ba);
  gb_kernel<<<(L * 32) / 256, 256, 0, stream>>>(ba, dtb, Alog, graw, beta);
  conv_silu<<<(L * (CONV_DIM / 4)) / 256, 256, 0, stream>>>(proj, convw, conv);
  l2norm_qk<<<(L * 32) / 4, 256, 0, stream>>>(conv);
  prep_T<<<NCH * 32, 256, 0, stream>>>(conv, graw, beta, cumg, Tg);
  prep_M<<<NCH * 32, 256, 0, stream>>>(conv, cumg, Mg);
  chunk_scan<<<32 * 8, 512, 0, stream>>>(conv, cumg, beta, Tg, Mg, core);
  post_kernel<<<(L * 32) / 4, 256, 0, stream>>>(core, proj, normw, gated_hi, gated_lo);
  transpose_split<<<dim3(HDIM / 32, VALUE_DIM / 32), 256, 0, stream>>>(Wout, Wot_hi, Wot_lo,
                                                                      VALUE_DIM, HDIM);
  mfma_gemm_split<<<dim3(HDIM / 128, L / 128), 256, 0, stream>>>(gated_hi, gated_lo, Wot_hi, Wot_lo,
                                                                 out, L, HDIM, VALUE_DIM);
}